// Round 2
// baseline (294.521 us; speedup 1.0000x reference)
//
#include <hip/hip_runtime.h>

// YOLO post-process, 2 kernels:
//  scan     : per (img, 1600-anchor chunk) exact streaming top-64, float4
//             loads, shuffle seed threshold, LDS candidate buffer. ALL
//             register arrays statically indexed (R4: runtime idx -> scratch).
//             R5 lesson: lane-granular monotone pruning REGRESSED (+6.5us) --
//             ~every wave had >=1 lane pass the gate, so exec-masked cost was
//             paid anyway plus argmax/branch overhead. Exhaustive is faster.
//  merge_nms: one block per image. Per level: sort chunk top-64 runs in LDS,
//             decode boxes for level top-64 into LDS; then stable sort 192 +
//             parallel IoU bit-matrix + greedy bit-sweep, write final out.
//             (R6: fused former merge+nms kernels -- total tracked scan 1:1,
//             so the ~205us remainder is dispatch overhead, not compute.)

#define NUM_CLASSES 5
#define CONF_THRESH 0.6f
#define NMS_THRESH  0.2f
#define TOPK   64
#define BATCH  128
#define TOTK   192
#define NCH    21      // per image: 16 (lvl0) + 4 (lvl1) + 1 (lvl2), 1600 anchors each
#define CHUNK  1600
#define SCAP   2048    // LDS candidate buffer (u64)
#define SOFT   768     // compact when cnt exceeds this; SOFT + 1280 <= SCAP

typedef unsigned long long u64;
typedef unsigned int u32;

// Descending bitonic sort of k[0..m) (m pow2), block-cooperative.
// First action is a barrier (covers preceding LDS writes); ends with a barrier.
__device__ void bitonic_desc(u64* k, int m) {
  for (int kk = 2; kk <= m; kk <<= 1) {
    for (int j = kk >> 1; j > 0; j >>= 1) {
      __syncthreads();
      for (int i = threadIdx.x; i < m; i += blockDim.x) {
        int ixj = i ^ j;
        if (ixj > i) {
          u64 a = k[i], b = k[ixj];
          bool sw = ((i & kk) == 0) ? (a < b) : (a > b);
          if (sw) { k[i] = b; k[ixj] = a; }
        }
      }
    }
  }
  __syncthreads();
}

// In-register bitonic sort of 64 values across one wave, descending by lane.
__device__ inline u64 wave_sort64_desc(u64 v, int lane) {
  #pragma unroll
  for (int k = 2; k <= 64; k <<= 1) {
    #pragma unroll
    for (int j = k >> 1; j > 0; j >>= 1) {
      u64 o = __shfl_xor(v, j, 64);
      bool keepMax = (((lane & k) == 0) != ((lane & j) != 0));
      v = keepMax ? (v > o ? v : o) : (v < o ? v : o);
    }
  }
  return v;
}

// score = sqrt(sigmoid(obj)*sigmoid(cls)); key = (score_bits<<32) | ~idx
// reproduces lax.top_k order (value desc, index asc). Bit-exact vs numpy
// (absmax 0.0 R2-R6) -- do not alter the float expressions.
__device__ inline u64 score_key(float so, float cv, int idx) {
  float sc = 1.0f / (1.0f + expf(-cv));
  float s  = sqrtf(__fmul_rn(so, sc));
  return ((u64)__float_as_uint(s) << 32) | (u32)(~(u32)idx);
}

__device__ inline float sigmoidf(float x) { return 1.0f / (1.0f + expf(-x)); }

__global__ __launch_bounds__(256) void scan_kernel(
    const float* __restrict__ obj8,  const float* __restrict__ cls8,
    const float* __restrict__ obj16, const float* __restrict__ cls16,
    const float* __restrict__ obj32, const float* __restrict__ cls32,
    u64* __restrict__ ws_part) {
  __shared__ u64 keys[SCAP];
  __shared__ int cnt;
  __shared__ u64 sthr[4];

  const int bx  = blockIdx.x;
  const int img = bx / NCH;
  const int c   = bx - img * NCH;
  const int t   = threadIdx.x;
  const int lane = t & 63, wv = t >> 6;

  const float *obj, *cls;
  int hw, off;
  if (c < 16)      { obj = obj8;  cls = cls8;  hw = 25600; off = c * CHUNK; }
  else if (c < 20) { obj = obj16; cls = cls16; hw = 6400;  off = (c - 16) * CHUNK; }
  else             { obj = obj32; cls = cls32; hw = 1600;  off = 0; }
  obj += (size_t)img * hw + off;
  cls += ((size_t)img * hw + off) * NUM_CLASSES;

  // ---- phase 1: anchors [0,1024), thread t owns 4 consecutive anchors.
  // kk[] is ONLY ever indexed by compile-time constants (full unroll) so it
  // stays in VGPRs. (R4 lesson: one runtime index -> whole array in scratch.)
  u64 kk[20];
  u64 mx;
  {
    const float4* c4 = (const float4*)cls + (size_t)t * 5;
    float4 q0 = c4[0], q1 = c4[1], q2 = c4[2], q3 = c4[3], q4 = c4[4];
    float4 ov = ((const float4*)obj)[t];
    float cv[20] = { q0.x,q0.y,q0.z,q0.w, q1.x,q1.y,q1.z,q1.w,
                     q2.x,q2.y,q2.z,q2.w, q3.x,q3.y,q3.z,q3.w,
                     q4.x,q4.y,q4.z,q4.w };
    float os[4] = { sigmoidf(ov.x), sigmoidf(ov.y), sigmoidf(ov.z), sigmoidf(ov.w) };
    int ga0 = off + 4 * t;
    #pragma unroll
    for (int a = 0; a < 4; ++a)
      #pragma unroll
      for (int j = 0; j < 5; ++j)
        kk[a * 5 + j] = score_key(os[a], cv[a * 5 + j], (ga0 + a) * NUM_CLASSES + j);
    mx = kk[0];
    #pragma unroll
    for (int i = 1; i < 20; ++i) if (kk[i] > mx) mx = kk[i];
  }
  // seed threshold: min over waves of (wave's 16th-largest thread-max).
  // Each wave has >=16 real keys >= its 16th -> >=64 keys >= seed overall.
  u64 srt = wave_sort64_desc(mx, lane);
  if (lane == 15) sthr[wv] = srt;
  if (t == 0) cnt = 0;
  __syncthreads();
  u64 thr;
  {
    u64 a0 = sthr[0], a1 = sthr[1], a2 = sthr[2], a3 = sthr[3];
    u64 mn = a0 < a1 ? a0 : a1;
    u64 mn2 = a2 < a3 ? a2 : a3;
    thr = (mn < mn2 ? mn : mn2) - 1ull;   // push iff key > thr  (key >= seed)
  }

  int cs = 0;
  // ---- push rounds 0..3 from retained kk (anchors [0,1024)) ----
  #pragma unroll
  for (int a = 0; a < 4; ++a) {
    #pragma unroll
    for (int j = 0; j < 5; ++j) {
      u64 key = kk[a * 5 + j];
      if (key > thr) { int p = atomicAdd(&cnt, 1); if (p < SCAP) keys[p] = key; }
    }
    __syncthreads();
    cs = cnt;
    __syncthreads();              // uniform snapshot before further pushes
    if (cs > SOFT) {              // rare: compact to top-64, tighten threshold
      int m = 64; while (m < cs) m <<= 1;
      for (int i = cs + t; i < m; i += 256) keys[i] = 0ull;
      bitonic_desc(keys, m);
      if (t == 0) cnt = TOPK;
      u64 nt = keys[TOPK - 1];
      __syncthreads();
      thr = nt; cs = TOPK;
    }
  }

  // ---- phase 2: anchors [1024,1600) (576), threads t<144, rounds 4..7 ----
  const bool act2 = (t < 144);
  if (act2) {
    const float4* c4 = (const float4*)cls + 1280 + (size_t)t * 5;
    float4 q0 = c4[0], q1 = c4[1], q2 = c4[2], q3 = c4[3], q4 = c4[4];
    float4 ov = ((const float4*)obj)[256 + t];
    float cv[20] = { q0.x,q0.y,q0.z,q0.w, q1.x,q1.y,q1.z,q1.w,
                     q2.x,q2.y,q2.z,q2.w, q3.x,q3.y,q3.z,q3.w,
                     q4.x,q4.y,q4.z,q4.w };
    float os[4] = { sigmoidf(ov.x), sigmoidf(ov.y), sigmoidf(ov.z), sigmoidf(ov.w) };
    int ga0 = off + 1024 + 4 * t;
    #pragma unroll
    for (int a = 0; a < 4; ++a)
      #pragma unroll
      for (int j = 0; j < 5; ++j)
        kk[a * 5 + j] = score_key(os[a], cv[a * 5 + j], (ga0 + a) * NUM_CLASSES + j);
  }
  #pragma unroll
  for (int a = 0; a < 4; ++a) {
    if (act2) {
      #pragma unroll
      for (int j = 0; j < 5; ++j) {
        u64 key = kk[a * 5 + j];
        if (key > thr) { int p = atomicAdd(&cnt, 1); if (p < SCAP) keys[p] = key; }
      }
    }
    __syncthreads();
    cs = cnt;
    __syncthreads();
    if (cs > SOFT) {
      int m = 64; while (m < cs) m <<= 1;
      for (int i = cs + t; i < m; i += 256) keys[i] = 0ull;
      bitonic_desc(keys, m);
      if (t == 0) cnt = TOPK;
      u64 nt = keys[TOPK - 1];
      __syncthreads();
      thr = nt; cs = TOPK;
    }
  }

  // ---- final sort, emit chunk top-64 (cnt >= 64 guaranteed by seed) ----
  {
    int m = 64; while (m < cs) m <<= 1;
    for (int i = cs + t; i < m; i += 256) keys[i] = 0ull;
    bitonic_desc(keys, m);
  }
  if (t < TOPK) ws_part[(size_t)bx * TOPK + t] = keys[t];
}

// One block (256 threads) per image: merge levels + decode + NMS, all in LDS.
__global__ __launch_bounds__(256) void merge_nms_kernel(
    const u64* __restrict__ ws_part,
    const float* __restrict__ reg8, const float* __restrict__ reg16, const float* __restrict__ reg32,
    float* __restrict__ out) {
  __shared__ u64   keys[1024];
  __shared__ float ssc[TOTK];
  __shared__ int   slb[TOTK];
  __shared__ float sbx[TOTK * 4];
  __shared__ u64   skeys[256];
  __shared__ float sX1[TOTK], sY1[TOTK], sX2[TOTK], sY2[TOTK], sA[TOTK];
  __shared__ u64   rows[TOTK * 3];
  __shared__ u64   svalid[3];
  __shared__ u64   skeep[3];
  __shared__ float lmarr[3];

  const int img = blockIdx.x;
  const int t   = threadIdx.x;

  // ---- merge phase: per level, sort chunk runs, decode level top-64 ----
  #pragma unroll
  for (int lvl = 0; lvl < 3; ++lvl) {
    const float* reg; int nchunk, cbase, w, hw; float stride;
    if (lvl == 0)      { reg = reg8;  nchunk = 16; cbase = 0;  w = 160; hw = 25600; stride = 8.0f;  }
    else if (lvl == 1) { reg = reg16; nchunk = 4;  cbase = 16; w = 80;  hw = 6400;  stride = 16.0f; }
    else               { reg = reg32; nchunk = 1;  cbase = 20; w = 40;  hw = 1600;  stride = 32.0f; }
    reg += (size_t)img * hw * 4;
    const int nk = nchunk * TOPK;                   // 1024 / 256 / 64 (pow2)
    const u64* src = ws_part + ((size_t)img * NCH + cbase) * TOPK;
    __syncthreads();   // protect keys[] reuse vs previous level's decode reads
    for (int i = t; i < nk; i += 256) keys[i] = src[i];
    bitonic_desc(keys, nk);   // starts with barrier (covers writes above)

    if (t < TOPK) {
      u64 key = keys[t];
      float s = __uint_as_float((u32)(key >> 32));
      u32 idx = ~((u32)key);
      int a = (int)(idx / NUM_CLASSES);
      int c = (int)(idx - (u32)a * NUM_CLASSES);
      int ix = a % w, iy = a / w;
      float ax = __fmul_rn((float)ix + 0.5f, stride);
      float ay = __fmul_rn((float)iy + 0.5f, stride);
      float r0 = reg[a*4+0], r1 = reg[a*4+1], r2 = reg[a*4+2], r3 = reg[a*4+3];
      float cx = __fadd_rn(__fmul_rn(r0, stride), ax);
      float cy = __fadd_rn(__fmul_rn(r1, stride), ay);
      float wd = __fmul_rn(expf(r2), stride);
      float ht = __fmul_rn(expf(r3), stride);
      float x1 = __fsub_rn(cx, __fmul_rn(0.5f, wd));
      float y1 = __fsub_rn(cy, __fmul_rn(0.5f, ht));
      float x2 = __fadd_rn(cx, __fmul_rn(0.5f, wd));
      float y2 = __fadd_rn(cy, __fmul_rn(0.5f, ht));
      int gi = lvl * TOPK + t;
      ssc[gi] = s;
      slb[gi] = c;
      sbx[gi*4+0] = x1; sbx[gi*4+1] = y1;
      sbx[gi*4+2] = x2; sbx[gi*4+3] = y2;
    }
  }
  __syncthreads();   // decode writes visible to all

  // ---- NMS phase (identical math to the former nms_kernel) ----
  if (t < TOTK) {
    float sc = ssc[t];
    float b0 = sbx[t*4+0], b1 = sbx[t*4+1];
    float b2 = sbx[t*4+2], b3 = sbx[t*4+3];
    skeys[t] = ((u64)__float_as_uint(sc) << 32) | (u32)(~(u32)t);
    float lm = fmaxf(fmaxf(fabsf(b0), fabsf(b1)), fmaxf(fabsf(b2), fabsf(b3)));
    #pragma unroll
    for (int d = 32; d > 0; d >>= 1) lm = fmaxf(lm, __shfl_xor(lm, d, 64));
    if ((t & 63) == 0) lmarr[t >> 6] = lm;
  } else {
    skeys[t] = 0ull;   // t in [192,256): zero keys sort to the tail
  }
  bitonic_desc(skeys, 256);   // starts with barrier (covers skeys/lmarr writes)

  const float lmAll = fmaxf(fmaxf(lmarr[0], lmarr[1]), lmarr[2]);
  const float offscale = __fadd_rn(__fmul_rn(2.0f, lmAll), 1.0f);

  float sc_r = 0.0f, X1 = 0.0f, Y1 = 0.0f, X2 = 0.0f, Y2 = 0.0f, A = 0.0f;
  int p = 0, lb_r = 0;
  if (t < TOTK) {
    u64 key = skeys[t];
    p = (int)(~((u32)key)) & 255;
    sc_r = __uint_as_float((u32)(key >> 32));
    lb_r = slb[p];
    float off = __fmul_rn((float)lb_r, offscale);
    X1 = __fadd_rn(sbx[p*4+0], off); Y1 = __fadd_rn(sbx[p*4+1], off);
    X2 = __fadd_rn(sbx[p*4+2], off); Y2 = __fadd_rn(sbx[p*4+3], off);
    A  = __fmul_rn(__fsub_rn(X2, X1), __fsub_rn(Y2, Y1));
    sX1[t] = X1; sY1[t] = Y1; sX2[t] = X2; sY2[t] = Y2; sA[t] = A;
  }
  {
    u64 bal = __ballot(sc_r > CONF_THRESH);
    int wv = t >> 6;
    if ((t & 63) == 0 && wv < 3) svalid[wv] = bal;
  }
  __syncthreads();

  if (t < TOTK) {
    u64 r0 = 0, r1 = 0, r2 = 0;
    for (int j = t + 1; j < TOTK; ++j) {
      float xx1 = fmaxf(X1, sX1[j]);
      float yy1 = fmaxf(Y1, sY1[j]);
      float xx2 = fminf(X2, sX2[j]);
      float yy2 = fminf(Y2, sY2[j]);
      float wv = fmaxf(1e-10f, __fsub_rn(xx2, xx1));
      float hv = fmaxf(1e-10f, __fsub_rn(yy2, yy1));
      float inter = __fmul_rn(wv, hv);
      float den = __fsub_rn(__fadd_rn(A, sA[j]), inter);
      float iou = __fdiv_rn(inter, den);
      if (iou > NMS_THRESH) {
        u64 b = 1ull << (j & 63);
        int wd = j >> 6;
        r0 |= (wd == 0) ? b : 0ull;
        r1 |= (wd == 1) ? b : 0ull;
        r2 |= (wd == 2) ? b : 0ull;
      }
    }
    rows[t*3+0] = r0; rows[t*3+1] = r1; rows[t*3+2] = r2;
  }
  __syncthreads();

  if (t < 64) {
    u64 k0 = svalid[0], k1 = svalid[1], k2 = svalid[2];
    #pragma unroll 4
    for (int i = 0; i < 64; ++i) {
      u64 m0 = rows[i*3+0], m1 = rows[i*3+1], m2 = rows[i*3+2];
      u64 sel = 0ull - ((k0 >> i) & 1ull);
      k0 &= ~(m0 & sel); k1 &= ~(m1 & sel); k2 &= ~(m2 & sel);
    }
    #pragma unroll 4
    for (int i = 0; i < 64; ++i) {
      int r = 64 + i;
      u64 m0 = rows[r*3+0], m1 = rows[r*3+1], m2 = rows[r*3+2];
      u64 sel = 0ull - ((k1 >> i) & 1ull);
      k0 &= ~(m0 & sel); k1 &= ~(m1 & sel); k2 &= ~(m2 & sel);
    }
    #pragma unroll 4
    for (int i = 0; i < 64; ++i) {
      int r = 128 + i;
      u64 m0 = rows[r*3+0], m1 = rows[r*3+1], m2 = rows[r*3+2];
      u64 sel = 0ull - ((k2 >> i) & 1ull);
      k0 &= ~(m0 & sel); k1 &= ~(m1 & sel); k2 &= ~(m2 & sel);
    }
    if (t == 0) { skeep[0] = k0; skeep[1] = k1; skeep[2] = k2; }
  }
  __syncthreads();

  if (t < TOTK) {
    float* out_boxes  = out;
    float* out_scores = out + (size_t)BATCH * TOTK * 4;
    float* out_labels = out + (size_t)BATCH * TOTK * 5;
    bool kp = (skeep[t >> 6] >> (t & 63)) & 1ull;
    int gi = img * TOTK + t;
    out_boxes[gi*4+0] = kp ? sbx[p*4+0] : 0.0f;
    out_boxes[gi*4+1] = kp ? sbx[p*4+1] : 0.0f;
    out_boxes[gi*4+2] = kp ? sbx[p*4+2] : 0.0f;
    out_boxes[gi*4+3] = kp ? sbx[p*4+3] : 0.0f;
    out_scores[gi] = kp ? sc_r : 0.0f;
    out_labels[gi] = kp ? (float)lb_r : -1.0f;
  }
}

extern "C" void kernel_launch(void* const* d_in, const int* in_sizes, int n_in,
                              void* d_out, int out_size, void* d_ws, size_t ws_size,
                              hipStream_t stream) {
  const float* obj8  = (const float*)d_in[0];
  const float* cls8  = (const float*)d_in[1];
  const float* reg8  = (const float*)d_in[2];
  const float* obj16 = (const float*)d_in[3];
  const float* cls16 = (const float*)d_in[4];
  const float* reg16 = (const float*)d_in[5];
  const float* obj32 = (const float*)d_in[6];
  const float* cls32 = (const float*)d_in[7];
  const float* reg32 = (const float*)d_in[8];

  // ws layout: part (2688*64 u64 = 1.376 MB)
  u64* ws_part = (u64*)d_ws;

  scan_kernel<<<dim3(BATCH * NCH), dim3(256), 0, stream>>>(
      obj8, cls8, obj16, cls16, obj32, cls32, ws_part);
  merge_nms_kernel<<<dim3(BATCH), dim3(256), 0, stream>>>(
      ws_part, reg8, reg16, reg32, (float*)d_out);
}

// Round 3
// 243.789 us; speedup vs baseline: 1.2081x; 1.2081x over previous
//
#include <hip/hip_runtime.h>

// YOLO post-process, 2 kernels:
//  scan     : per (img, 1600-anchor chunk) exact streaming top-64, float4
//             loads, shuffle seed threshold, LDS candidate buffer. ALL
//             register arrays statically indexed (R4: runtime idx -> scratch).
//             R5 lesson: lane-granular monotone pruning REGRESSED -- wave-
//             granular exec masks mean ~every wave pays the full cost anyway.
//  merge_nms: one block per image. R7 rewrite: the former LDS bitonic FULL
//             sorts (55+36 barrier passes, 7% VALUBusy, 89.7us) are replaced
//             by in-register wave merges of already-sorted runs:
//             top64(2 sorted 64-runs) = elementwise max(A[l], B[63-l])
//             (bitonic half-cleaner) + 6-stage shfl_xor descending merge.
//             Barrier epochs ~91 -> ~6. Bit-exact: u64 key total order makes
//             merge-of-sorted-runs identical to full-sort-then-truncate.

#define NUM_CLASSES 5
#define CONF_THRESH 0.6f
#define NMS_THRESH  0.2f
#define TOPK   64
#define BATCH  128
#define TOTK   192
#define NCH    21      // per image: 16 (lvl0) + 4 (lvl1) + 1 (lvl2), 1600 anchors each
#define CHUNK  1600
#define SCAP   2048    // LDS candidate buffer (u64)
#define SOFT   768     // compact when cnt exceeds this; SOFT + 1280 <= SCAP

typedef unsigned long long u64;
typedef unsigned int u32;

// Descending bitonic sort of k[0..m) (m pow2), block-cooperative.
// First action is a barrier (covers preceding LDS writes); ends with a barrier.
__device__ void bitonic_desc(u64* k, int m) {
  for (int kk = 2; kk <= m; kk <<= 1) {
    for (int j = kk >> 1; j > 0; j >>= 1) {
      __syncthreads();
      for (int i = threadIdx.x; i < m; i += blockDim.x) {
        int ixj = i ^ j;
        if (ixj > i) {
          u64 a = k[i], b = k[ixj];
          bool sw = ((i & kk) == 0) ? (a < b) : (a > b);
          if (sw) { k[i] = b; k[ixj] = a; }
        }
      }
    }
  }
  __syncthreads();
}

// In-register bitonic sort of 64 values across one wave, descending by lane.
__device__ inline u64 wave_sort64_desc(u64 v, int lane) {
  #pragma unroll
  for (int k = 2; k <= 64; k <<= 1) {
    #pragma unroll
    for (int j = k >> 1; j > 0; j >>= 1) {
      u64 o = __shfl_xor(v, j, 64);
      bool keepMax = (((lane & k) == 0) != ((lane & j) != 0));
      v = keepMax ? (v > o ? v : o) : (v < o ? v : o);
    }
  }
  return v;
}

__device__ __forceinline__ u64 u64max(u64 a, u64 b) { return a > b ? a : b; }
__device__ __forceinline__ u64 u64min(u64 a, u64 b) { return a < b ? a : b; }

// Descending bitonic MERGE of a bitonic 64-seq held one elem/lane.
__device__ __forceinline__ u64 bmerge64_desc(u64 v, int lane) {
  #pragma unroll
  for (int j = 32; j > 0; j >>= 1) {
    u64 o = __shfl_xor(v, j, 64);
    v = ((lane & j) == 0) ? u64max(v, o) : u64min(v, o);
  }
  return v;
}

// a = A[lane] (A desc-sorted), brev = B[63-lane] (B desc-sorted).
// Returns lane-th element of the desc-sorted top-64 of A∪B.
// (A ++ rev(B) is bitonic; dist-64 half-cleaner keeps the 64 largest,
//  result is bitonic; 6-stage merge sorts it desc.)
__device__ __forceinline__ u64 merge_top64(u64 a, u64 brev, int lane) {
  return bmerge64_desc(u64max(a, brev), lane);
}

// Top-64 of four desc-sorted 64-runs (b, d pre-reversed by caller's indexing).
__device__ __forceinline__ u64 merge4_top64(u64 a, u64 brev, u64 c, u64 drev, int lane) {
  u64 ab = merge_top64(a, brev, lane);
  u64 cd = merge_top64(c, drev, lane);
  u64 cdr = __shfl(cd, 63 - lane, 64);
  return merge_top64(ab, cdr, lane);
}

// score = sqrt(sigmoid(obj)*sigmoid(cls)); key = (score_bits<<32) | ~idx
// reproduces lax.top_k order (value desc, index asc). Bit-exact vs numpy
// (absmax 0.0 R2-R6) -- do not alter the float expressions.
__device__ inline u64 score_key(float so, float cv, int idx) {
  float sc = 1.0f / (1.0f + expf(-cv));
  float s  = sqrtf(__fmul_rn(so, sc));
  return ((u64)__float_as_uint(s) << 32) | (u32)(~(u32)idx);
}

__device__ inline float sigmoidf(float x) { return 1.0f / (1.0f + expf(-x)); }

__global__ __launch_bounds__(256) void scan_kernel(
    const float* __restrict__ obj8,  const float* __restrict__ cls8,
    const float* __restrict__ obj16, const float* __restrict__ cls16,
    const float* __restrict__ obj32, const float* __restrict__ cls32,
    u64* __restrict__ ws_part) {
  __shared__ u64 keys[SCAP];
  __shared__ int cnt;
  __shared__ u64 sthr[4];

  const int bx  = blockIdx.x;
  const int img = bx / NCH;
  const int c   = bx - img * NCH;
  const int t   = threadIdx.x;
  const int lane = t & 63, wv = t >> 6;

  const float *obj, *cls;
  int hw, off;
  if (c < 16)      { obj = obj8;  cls = cls8;  hw = 25600; off = c * CHUNK; }
  else if (c < 20) { obj = obj16; cls = cls16; hw = 6400;  off = (c - 16) * CHUNK; }
  else             { obj = obj32; cls = cls32; hw = 1600;  off = 0; }
  obj += (size_t)img * hw + off;
  cls += ((size_t)img * hw + off) * NUM_CLASSES;

  // ---- phase 1: anchors [0,1024), thread t owns 4 consecutive anchors.
  // kk[] is ONLY ever indexed by compile-time constants (full unroll) so it
  // stays in VGPRs. (R4 lesson: one runtime index -> whole array in scratch.)
  u64 kk[20];
  u64 mx;
  {
    const float4* c4 = (const float4*)cls + (size_t)t * 5;
    float4 q0 = c4[0], q1 = c4[1], q2 = c4[2], q3 = c4[3], q4 = c4[4];
    float4 ov = ((const float4*)obj)[t];
    float cv[20] = { q0.x,q0.y,q0.z,q0.w, q1.x,q1.y,q1.z,q1.w,
                     q2.x,q2.y,q2.z,q2.w, q3.x,q3.y,q3.z,q3.w,
                     q4.x,q4.y,q4.z,q4.w };
    float os[4] = { sigmoidf(ov.x), sigmoidf(ov.y), sigmoidf(ov.z), sigmoidf(ov.w) };
    int ga0 = off + 4 * t;
    #pragma unroll
    for (int a = 0; a < 4; ++a)
      #pragma unroll
      for (int j = 0; j < 5; ++j)
        kk[a * 5 + j] = score_key(os[a], cv[a * 5 + j], (ga0 + a) * NUM_CLASSES + j);
    mx = kk[0];
    #pragma unroll
    for (int i = 1; i < 20; ++i) if (kk[i] > mx) mx = kk[i];
  }
  // seed threshold: min over waves of (wave's 16th-largest thread-max).
  // Each wave has >=16 real keys >= its 16th -> >=64 keys >= seed overall.
  u64 srt = wave_sort64_desc(mx, lane);
  if (lane == 15) sthr[wv] = srt;
  if (t == 0) cnt = 0;
  __syncthreads();
  u64 thr;
  {
    u64 a0 = sthr[0], a1 = sthr[1], a2 = sthr[2], a3 = sthr[3];
    u64 mn = a0 < a1 ? a0 : a1;
    u64 mn2 = a2 < a3 ? a2 : a3;
    thr = (mn < mn2 ? mn : mn2) - 1ull;   // push iff key > thr  (key >= seed)
  }

  int cs = 0;
  // ---- push rounds 0..3 from retained kk (anchors [0,1024)) ----
  #pragma unroll
  for (int a = 0; a < 4; ++a) {
    #pragma unroll
    for (int j = 0; j < 5; ++j) {
      u64 key = kk[a * 5 + j];
      if (key > thr) { int p = atomicAdd(&cnt, 1); if (p < SCAP) keys[p] = key; }
    }
    __syncthreads();
    cs = cnt;
    __syncthreads();              // uniform snapshot before further pushes
    if (cs > SOFT) {              // rare: compact to top-64, tighten threshold
      int m = 64; while (m < cs) m <<= 1;
      for (int i = cs + t; i < m; i += 256) keys[i] = 0ull;
      bitonic_desc(keys, m);
      if (t == 0) cnt = TOPK;
      u64 nt = keys[TOPK - 1];
      __syncthreads();
      thr = nt; cs = TOPK;
    }
  }

  // ---- phase 2: anchors [1024,1600) (576), threads t<144, rounds 4..7 ----
  const bool act2 = (t < 144);
  if (act2) {
    const float4* c4 = (const float4*)cls + 1280 + (size_t)t * 5;
    float4 q0 = c4[0], q1 = c4[1], q2 = c4[2], q3 = c4[3], q4 = c4[4];
    float4 ov = ((const float4*)obj)[256 + t];
    float cv[20] = { q0.x,q0.y,q0.z,q0.w, q1.x,q1.y,q1.z,q1.w,
                     q2.x,q2.y,q2.z,q2.w, q3.x,q3.y,q3.z,q3.w,
                     q4.x,q4.y,q4.z,q4.w };
    float os[4] = { sigmoidf(ov.x), sigmoidf(ov.y), sigmoidf(ov.z), sigmoidf(ov.w) };
    int ga0 = off + 1024 + 4 * t;
    #pragma unroll
    for (int a = 0; a < 4; ++a)
      #pragma unroll
      for (int j = 0; j < 5; ++j)
        kk[a * 5 + j] = score_key(os[a], cv[a * 5 + j], (ga0 + a) * NUM_CLASSES + j);
  }
  #pragma unroll
  for (int a = 0; a < 4; ++a) {
    if (act2) {
      #pragma unroll
      for (int j = 0; j < 5; ++j) {
        u64 key = kk[a * 5 + j];
        if (key > thr) { int p = atomicAdd(&cnt, 1); if (p < SCAP) keys[p] = key; }
      }
    }
    __syncthreads();
    cs = cnt;
    __syncthreads();
    if (cs > SOFT) {
      int m = 64; while (m < cs) m <<= 1;
      for (int i = cs + t; i < m; i += 256) keys[i] = 0ull;
      bitonic_desc(keys, m);
      if (t == 0) cnt = TOPK;
      u64 nt = keys[TOPK - 1];
      __syncthreads();
      thr = nt; cs = TOPK;
    }
  }

  // ---- final sort, emit chunk top-64 (cnt >= 64 guaranteed by seed) ----
  {
    int m = 64; while (m < cs) m <<= 1;
    for (int i = cs + t; i < m; i += 256) keys[i] = 0ull;
    bitonic_desc(keys, m);
  }
  if (t < TOPK) ws_part[(size_t)bx * TOPK + t] = keys[t];
}

// One block (256 threads = 4 waves) per image: merge levels + decode + NMS.
__global__ __launch_bounds__(256) void merge_nms_kernel(
    const u64* __restrict__ ws_part,
    const float* __restrict__ reg8, const float* __restrict__ reg16, const float* __restrict__ reg32,
    float* __restrict__ out) {
  __shared__ u64   lds_runs[256];     // round-A lvl0 intermediate runs
  __shared__ u64   lvlkeys[TOTK];     // final per-level top-64 keys (concat order)
  __shared__ u64   skeys[TOTK];       // NMS-sorted keys
  __shared__ int   slb[TOTK];
  __shared__ float sbx[TOTK * 4];
  __shared__ float sX1[TOTK], sY1[TOTK], sX2[TOTK], sY2[TOTK], sA[TOTK];
  __shared__ u64   rows[TOTK * 3];
  __shared__ u64   svalid[3];
  __shared__ u64   skeep[3];
  __shared__ float lmarr[3];

  const int img  = blockIdx.x;
  const int t    = threadIdx.x;
  const int lane = t & 63, wv = t >> 6;

  const u64* pbase = ws_part + (size_t)img * NCH * TOPK;

  // ---- round A: 4 waves x top64-of-4-runs covers lvl0's 16 runs ----
  {
    const u64* q = pbase + (size_t)(4 * wv) * TOPK;
    u64 a    = q[lane];
    u64 brev = q[64 + 63 - lane];
    u64 c    = q[128 + lane];
    u64 drev = q[192 + 63 - lane];
    lds_runs[wv * 64 + lane] = merge4_top64(a, brev, c, drev, lane);
    if (wv == 3) lvlkeys[128 + lane] = pbase[20 * TOPK + lane];  // lvl2 final
  }
  __syncthreads();

  // ---- round B: wave0 -> lvl0 final (from LDS), wave1 -> lvl1 final ----
  if (wv == 0) {
    u64 a    = lds_runs[lane];
    u64 brev = lds_runs[64 + 63 - lane];
    u64 c    = lds_runs[128 + lane];
    u64 drev = lds_runs[192 + 63 - lane];
    lvlkeys[lane] = merge4_top64(a, brev, c, drev, lane);
  } else if (wv == 1) {
    const u64* q = pbase + (size_t)16 * TOPK;
    u64 a    = q[lane];
    u64 brev = q[64 + 63 - lane];
    u64 c    = q[128 + lane];
    u64 drev = q[192 + 63 - lane];
    lvlkeys[64 + lane] = merge4_top64(a, brev, c, drev, lane);
  }
  __syncthreads();

  // ---- wave0: in-register 192 sort (3 desc runs -> full desc merge).
  //      NMS key = (score_bits<<32) | ~t; each level's 64 keys are already
  //      desc-sorted wrt this key (score desc, tie -> smaller t first).
  //      waves 1-3: decode boxes/labels for the 192 entries (one lvl each).
  if (wv == 0) {
    const u64 HIMASK = 0xFFFFFFFF00000000ull;
    u64 s0 = (lvlkeys[lane] & HIMASK) | (u32)(~(u32)lane);
    int i1 = 64 + 63 - lane;
    u64 s1r = (lvlkeys[i1] & HIMASK) | (u32)(~(u32)i1);
    int i2 = 128 + 63 - lane;
    u64 s2r = (lvlkeys[i2] & HIMASK) | (u32)(~(u32)i2);
    // M1: full desc merge of run0,run1 -> S1 = [hi_ ++ lo_] (128, desc)
    u64 hi_ = bmerge64_desc(u64max(s0, s1r), lane);
    u64 lo_ = bmerge64_desc(u64min(s0, s1r), lane);
    // M2: merge S1 with S2 = run2 ++ zeros (desc 128). Input [S1 ++ rev(S2)]
    // is bitonic 256; half-cleaners + 6-stage merges; positions 192..255 are
    // the zero pad, discarded.
    u64 R1   = u64max(lo_, s2r);
    u64 out0 = bmerge64_desc(u64max(hi_, R1), lane);
    u64 out1 = bmerge64_desc(u64min(hi_, R1), lane);
    u64 out2 = bmerge64_desc(u64min(lo_, s2r), lane);
    skeys[lane]       = out0;
    skeys[64 + lane]  = out1;
    skeys[128 + lane] = out2;
  } else {
    int idx = t - 64;                  // 0..191; lvl = wv-1 (uniform per wave)
    const float* reg; int w; int hw; float stride;
    if (wv == 1)      { reg = reg8;  w = 160; hw = 25600; stride = 8.0f;  }
    else if (wv == 2) { reg = reg16; w = 80;  hw = 6400;  stride = 16.0f; }
    else              { reg = reg32; w = 40;  hw = 1600;  stride = 32.0f; }
    reg += (size_t)img * hw * 4;
    u64 key = lvlkeys[idx];
    u32 raw = ~((u32)key);
    int a = (int)(raw / NUM_CLASSES);
    int c = (int)(raw - (u32)a * NUM_CLASSES);
    int ix = a % w, iy = a / w;
    float ax = __fmul_rn((float)ix + 0.5f, stride);
    float ay = __fmul_rn((float)iy + 0.5f, stride);
    float r0 = reg[a*4+0], r1 = reg[a*4+1], r2 = reg[a*4+2], r3 = reg[a*4+3];
    float cx = __fadd_rn(__fmul_rn(r0, stride), ax);
    float cy = __fadd_rn(__fmul_rn(r1, stride), ay);
    float wd = __fmul_rn(expf(r2), stride);
    float ht = __fmul_rn(expf(r3), stride);
    float x1 = __fsub_rn(cx, __fmul_rn(0.5f, wd));
    float y1 = __fsub_rn(cy, __fmul_rn(0.5f, ht));
    float x2 = __fadd_rn(cx, __fmul_rn(0.5f, wd));
    float y2 = __fadd_rn(cy, __fmul_rn(0.5f, ht));
    slb[idx] = c;
    sbx[idx*4+0] = x1; sbx[idx*4+1] = y1;
    sbx[idx*4+2] = x2; sbx[idx*4+3] = y2;
  }
  __syncthreads();

  // ---- NMS setup: per-thread box (sorted order), global |box| max ----
  float sc_r = 0.0f, b0 = 0.0f, b1 = 0.0f, b2 = 0.0f, b3 = 0.0f;
  int p = 0, lb_r = 0;
  if (t < TOTK) {
    u64 key = skeys[t];
    p = (int)(~((u32)key)) & 255;
    sc_r = __uint_as_float((u32)(key >> 32));
    lb_r = slb[p];
    b0 = sbx[p*4+0]; b1 = sbx[p*4+1]; b2 = sbx[p*4+2]; b3 = sbx[p*4+3];
    float lm = fmaxf(fmaxf(fabsf(b0), fabsf(b1)), fmaxf(fabsf(b2), fabsf(b3)));
    #pragma unroll
    for (int d = 32; d > 0; d >>= 1) lm = fmaxf(lm, __shfl_xor(lm, d, 64));
    if (lane == 0) lmarr[wv] = lm;
  }
  __syncthreads();

  const float lmAll = fmaxf(fmaxf(lmarr[0], lmarr[1]), lmarr[2]);
  const float offscale = __fadd_rn(__fmul_rn(2.0f, lmAll), 1.0f);

  float X1 = 0.0f, Y1 = 0.0f, X2 = 0.0f, Y2 = 0.0f, A = 0.0f;
  if (t < TOTK) {
    float off = __fmul_rn((float)lb_r, offscale);
    X1 = __fadd_rn(b0, off); Y1 = __fadd_rn(b1, off);
    X2 = __fadd_rn(b2, off); Y2 = __fadd_rn(b3, off);
    A  = __fmul_rn(__fsub_rn(X2, X1), __fsub_rn(Y2, Y1));
    sX1[t] = X1; sY1[t] = Y1; sX2[t] = X2; sY2[t] = Y2; sA[t] = A;
    u64 bal = __ballot(sc_r > CONF_THRESH);
    if (lane == 0) svalid[wv] = bal;
  }
  __syncthreads();

  if (t < TOTK) {
    u64 r0m = 0, r1m = 0, r2m = 0;
    for (int j = t + 1; j < TOTK; ++j) {
      float xx1 = fmaxf(X1, sX1[j]);
      float yy1 = fmaxf(Y1, sY1[j]);
      float xx2 = fminf(X2, sX2[j]);
      float yy2 = fminf(Y2, sY2[j]);
      float wv2 = fmaxf(1e-10f, __fsub_rn(xx2, xx1));
      float hv = fmaxf(1e-10f, __fsub_rn(yy2, yy1));
      float inter = __fmul_rn(wv2, hv);
      float den = __fsub_rn(__fadd_rn(A, sA[j]), inter);
      float iou = __fdiv_rn(inter, den);
      if (iou > NMS_THRESH) {
        u64 b = 1ull << (j & 63);
        int wd = j >> 6;
        r0m |= (wd == 0) ? b : 0ull;
        r1m |= (wd == 1) ? b : 0ull;
        r2m |= (wd == 2) ? b : 0ull;
      }
    }
    rows[t*3+0] = r0m; rows[t*3+1] = r1m; rows[t*3+2] = r2m;
  }
  __syncthreads();

  if (t < 64) {
    u64 k0 = svalid[0], k1 = svalid[1], k2 = svalid[2];
    #pragma unroll 4
    for (int i = 0; i < 64; ++i) {
      u64 m0 = rows[i*3+0], m1 = rows[i*3+1], m2 = rows[i*3+2];
      u64 sel = 0ull - ((k0 >> i) & 1ull);
      k0 &= ~(m0 & sel); k1 &= ~(m1 & sel); k2 &= ~(m2 & sel);
    }
    #pragma unroll 4
    for (int i = 0; i < 64; ++i) {
      int r = 64 + i;
      u64 m0 = rows[r*3+0], m1 = rows[r*3+1], m2 = rows[r*3+2];
      u64 sel = 0ull - ((k1 >> i) & 1ull);
      k0 &= ~(m0 & sel); k1 &= ~(m1 & sel); k2 &= ~(m2 & sel);
    }
    #pragma unroll 4
    for (int i = 0; i < 64; ++i) {
      int r = 128 + i;
      u64 m0 = rows[r*3+0], m1 = rows[r*3+1], m2 = rows[r*3+2];
      u64 sel = 0ull - ((k2 >> i) & 1ull);
      k0 &= ~(m0 & sel); k1 &= ~(m1 & sel); k2 &= ~(m2 & sel);
    }
    if (t == 0) { skeep[0] = k0; skeep[1] = k1; skeep[2] = k2; }
  }
  __syncthreads();

  if (t < TOTK) {
    float* out_boxes  = out;
    float* out_scores = out + (size_t)BATCH * TOTK * 4;
    float* out_labels = out + (size_t)BATCH * TOTK * 5;
    bool kp = (skeep[t >> 6] >> (t & 63)) & 1ull;
    int gi = img * TOTK + t;
    out_boxes[gi*4+0] = kp ? sbx[p*4+0] : 0.0f;
    out_boxes[gi*4+1] = kp ? sbx[p*4+1] : 0.0f;
    out_boxes[gi*4+2] = kp ? sbx[p*4+2] : 0.0f;
    out_boxes[gi*4+3] = kp ? sbx[p*4+3] : 0.0f;
    out_scores[gi] = kp ? sc_r : 0.0f;
    out_labels[gi] = kp ? (float)lb_r : -1.0f;
  }
}

extern "C" void kernel_launch(void* const* d_in, const int* in_sizes, int n_in,
                              void* d_out, int out_size, void* d_ws, size_t ws_size,
                              hipStream_t stream) {
  const float* obj8  = (const float*)d_in[0];
  const float* cls8  = (const float*)d_in[1];
  const float* reg8  = (const float*)d_in[2];
  const float* obj16 = (const float*)d_in[3];
  const float* cls16 = (const float*)d_in[4];
  const float* reg16 = (const float*)d_in[5];
  const float* obj32 = (const float*)d_in[6];
  const float* cls32 = (const float*)d_in[7];
  const float* reg32 = (const float*)d_in[8];

  // ws layout: part (2688*64 u64 = 1.376 MB)
  u64* ws_part = (u64*)d_ws;

  scan_kernel<<<dim3(BATCH * NCH), dim3(256), 0, stream>>>(
      obj8, cls8, obj16, cls16, obj32, cls32, ws_part);
  merge_nms_kernel<<<dim3(BATCH), dim3(256), 0, stream>>>(
      ws_part, reg8, reg16, reg32, (float*)d_out);
}

// Round 4
// 240.079 us; speedup vs baseline: 1.2268x; 1.0155x over previous
//
#include <hip/hip_runtime.h>

// YOLO post-process, 2 kernels:
//  scan     : per (img, 1600-anchor chunk) exact streaming top-64.
//             R8 rewrite: 320 threads (5 anchors/thread, no idle phase-2).
//             Cheap conservative bound prod=(1+e^-o)(1+e^-c) ~ 1/score^2
//             (fast __expf, ~6 VALU/key) gates candidates into a dense LDS
//             WORKLIST; exact OCML score_key (~35 VALU/key) runs only on the
//             compacted worklist (~90/chunk instead of 8000).
//             R5 lesson: exec-mask-granular pruning saves nothing (every wave
//             has a passing lane) -- compaction-based pruning is the fix.
//             Margins: fast-op rel err <= ~2e-6; gates use 1e-4 (50x slack),
//             exact `key > thr` filter unchanged -> push set bit-identical.
//  merge_nms: one block per image; in-register wave merges of sorted runs
//             (R7: top64(A,B) = max(A[l],B[63-l]) + 6-stage shfl bitonic
//             merge; barrier epochs ~91 -> ~6; was 89.7us of LDS full sorts).

#define NUM_CLASSES 5
#define CONF_THRESH 0.6f
#define NMS_THRESH  0.2f
#define TOPK   64
#define BATCH  128
#define TOTK   192
#define NCH    21      // per image: 16 (lvl0) + 4 (lvl1) + 1 (lvl2), 1600 anchors each
#define CHUNK  1600
#define SCAP   2048    // LDS candidate buffer (u64)
#define SOFT   448     // compact when cnt exceeds this; SOFT + 1600 <= SCAP
#define NTHR   320     // 5 waves; 1600 anchors = 5/thread, zero idle lanes
#define WCAP   1600    // worklist cap = NTHR * 5 pushes/round (proof-bound)

typedef unsigned long long u64;
typedef unsigned int u32;

// Descending bitonic sort of k[0..m) (m pow2), block-cooperative.
// First action is a barrier (covers preceding LDS writes); ends with a barrier.
__device__ void bitonic_desc(u64* k, int m) {
  for (int kk = 2; kk <= m; kk <<= 1) {
    for (int j = kk >> 1; j > 0; j >>= 1) {
      __syncthreads();
      for (int i = threadIdx.x; i < m; i += blockDim.x) {
        int ixj = i ^ j;
        if (ixj > i) {
          u64 a = k[i], b = k[ixj];
          bool sw = ((i & kk) == 0) ? (a < b) : (a > b);
          if (sw) { k[i] = b; k[ixj] = a; }
        }
      }
    }
  }
  __syncthreads();
}

// In-register bitonic sort of 64 u32 across one wave, descending by lane.
__device__ inline u32 wave_sort64_desc_u32(u32 v, int lane) {
  #pragma unroll
  for (int k = 2; k <= 64; k <<= 1) {
    #pragma unroll
    for (int j = k >> 1; j > 0; j >>= 1) {
      u32 o = __shfl_xor(v, j, 64);
      bool keepMax = (((lane & k) == 0) != ((lane & j) != 0));
      v = keepMax ? (v > o ? v : o) : (v < o ? v : o);
    }
  }
  return v;
}

__device__ __forceinline__ u64 u64max(u64 a, u64 b) { return a > b ? a : b; }
__device__ __forceinline__ u64 u64min(u64 a, u64 b) { return a < b ? a : b; }

// Descending bitonic MERGE of a bitonic 64-seq held one elem/lane.
__device__ __forceinline__ u64 bmerge64_desc(u64 v, int lane) {
  #pragma unroll
  for (int j = 32; j > 0; j >>= 1) {
    u64 o = __shfl_xor(v, j, 64);
    v = ((lane & j) == 0) ? u64max(v, o) : u64min(v, o);
  }
  return v;
}

__device__ __forceinline__ u64 merge_top64(u64 a, u64 brev, int lane) {
  return bmerge64_desc(u64max(a, brev), lane);
}

__device__ __forceinline__ u64 merge4_top64(u64 a, u64 brev, u64 c, u64 drev, int lane) {
  u64 ab = merge_top64(a, brev, lane);
  u64 cd = merge_top64(c, drev, lane);
  u64 cdr = __shfl(cd, 63 - lane, 64);
  return merge_top64(ab, cdr, lane);
}

// score = sqrt(sigmoid(obj)*sigmoid(cls)); key = (score_bits<<32) | ~idx
// reproduces lax.top_k order (value desc, index asc). Bit-exact vs numpy
// (absmax 0.0 R2-R7) -- do not alter the float expressions.
__device__ inline u64 score_key(float so, float cv, int idx) {
  float sc = 1.0f / (1.0f + expf(-cv));
  float s  = sqrtf(__fmul_rn(so, sc));
  return ((u64)__float_as_uint(s) << 32) | (u32)(~(u32)idx);
}

__device__ inline float sigmoidf(float x) { return 1.0f / (1.0f + expf(-x)); }

__global__ __launch_bounds__(NTHR) void scan_kernel(
    const float* __restrict__ obj8,  const float* __restrict__ cls8,
    const float* __restrict__ obj16, const float* __restrict__ cls16,
    const float* __restrict__ obj32, const float* __restrict__ cls32,
    u64* __restrict__ ws_part) {
  __shared__ u64 keys[SCAP];
  __shared__ u32 wl[WCAP];
  __shared__ int cnt;
  __shared__ int wcnt;
  __shared__ u32 sthr[5];

  const int bx  = blockIdx.x;
  const int img = bx / NCH;
  const int c   = bx - img * NCH;
  const int t   = threadIdx.x;
  const int lane = t & 63, wv = t >> 6;

  const float *obj, *cls;
  int hw, off;
  if (c < 16)      { obj = obj8;  cls = cls8;  hw = 25600; off = c * CHUNK; }
  else if (c < 20) { obj = obj16; cls = cls16; hw = 6400;  off = (c - 16) * CHUNK; }
  else             { obj = obj32; cls = cls32; hw = 1600;  off = 0; }
  obj += (size_t)img * hw + off;
  cls += ((size_t)img * hw + off) * NUM_CLASSES;

  // ---- cheap bound pass: ff[a*5+j] = (1+e^-obj)(1+e^-cls) ~= 1/score^2
  // (monotone DECREASING in score; fast ops, rel err <= ~2e-6).
  // ff[] only indexed by compile-time constants -> stays in VGPRs (R4).
  float ff[25];
  {
    #pragma unroll
    for (int a = 0; a < 5; ++a) {
      float o = obj[a * NTHR + t];
      float dob = 1.0f + __expf(-o);
      #pragma unroll
      for (int j = 0; j < 5; ++j) {
        float cvv = cls[(a * NTHR + t) * 5 + j];
        ff[a * 5 + j] = dob * (1.0f + __expf(-cvv));
      }
    }
  }
  // seed: per-wave 16th-smallest thread-min-prod (= 16th-largest fast score).
  // >=16 threads/wave have min-prod <= their wave's p16 <= pmax -> their TRUE
  // max score >= sqrt(1/pmax)*(1-eps) = ts. 5 waves -> >=80 exact keys >= ts.
  float pmin = ff[0];
  #pragma unroll
  for (int i = 1; i < 25; ++i) pmin = fminf(pmin, ff[i]);
  u32 srt = wave_sort64_desc_u32(__float_as_uint(pmin), lane);
  if (lane == 48) sthr[wv] = srt;        // 16th smallest = 49th largest
  if (t == 0) { cnt = 0; wcnt = 0; }
  __syncthreads();
  u64 thr; float thr_inv;
  {
    float pmax = __uint_as_float(sthr[0]);
    pmax = fmaxf(pmax, __uint_as_float(sthr[1]));
    pmax = fmaxf(pmax, __uint_as_float(sthr[2]));
    pmax = fmaxf(pmax, __uint_as_float(sthr[3]));
    pmax = fmaxf(pmax, __uint_as_float(sthr[4]));
    float ts = sqrtf(__fdiv_rn(1.0f, pmax)) * (1.0f - 1e-4f);
    // key > thr  <=>  score_bits >= bits(ts)  <=>  score >= ts
    thr = ((u64)__float_as_uint(ts) << 32) - 1ull;
    // gate: prod <= thr_inv  <==  score >= ts (with 2e-4 conservative slack)
    thr_inv = __fdiv_rn(1.0f, __fmul_rn(__fmul_rn(ts, ts), 1.0f - 2e-4f));
  }

  int cs = 0;
  // ---- 5 anchor-rounds: gate -> dense exact over compacted worklist ----
  #pragma unroll
  for (int a = 0; a < 5; ++a) {
    #pragma unroll
    for (int j = 0; j < 5; ++j) {
      if (ff[a * 5 + j] <= thr_inv) {
        int p = atomicAdd(&wcnt, 1);          // p < WCAP by construction
        wl[p] = (u32)(((a * NTHR + t) << 3) | j);
      }
    }
    __syncthreads();
    int wc = wcnt;
    for (int i = t; i < wc; i += NTHR) {      // dense: every lane a survivor
      u32 cd = wl[i];
      int al = (int)(cd >> 3);
      int jj = (int)(cd & 7u);
      float o   = obj[al];
      float cvv = cls[al * 5 + jj];
      u64 key = score_key(sigmoidf(o), cvv, (off + al) * NUM_CLASSES + jj);
      if (key > thr) { int p = atomicAdd(&cnt, 1); if (p < SCAP) keys[p] = key; }
    }
    __syncthreads();
    if (t == 0) wcnt = 0;
    cs = cnt;
    __syncthreads();              // uniform snapshot; covers wcnt reset
    if (cs > SOFT) {              // rare: compact to top-64, tighten threshold
      int m = 64; while (m < cs) m <<= 1;
      for (int i = cs + t; i < m; i += NTHR) keys[i] = 0ull;
      bitonic_desc(keys, m);
      if (t == 0) cnt = TOPK;
      u64 nt = keys[TOPK - 1];
      __syncthreads();
      thr = nt; cs = TOPK;
      float tsc = __uint_as_float((u32)(nt >> 32));   // > 0 (real key)
      thr_inv = __fdiv_rn(1.0f, __fmul_rn(__fmul_rn(tsc, tsc), 1.0f - 2e-4f));
    }
  }

  // ---- final sort, emit chunk top-64 (cnt >= 64 guaranteed by seed) ----
  {
    int m = 64; while (m < cs) m <<= 1;
    for (int i = cs + t; i < m; i += NTHR) keys[i] = 0ull;
    bitonic_desc(keys, m);
  }
  if (t < TOPK) ws_part[(size_t)bx * TOPK + t] = keys[t];
}

// One block (256 threads = 4 waves) per image: merge levels + decode + NMS.
__global__ __launch_bounds__(256) void merge_nms_kernel(
    const u64* __restrict__ ws_part,
    const float* __restrict__ reg8, const float* __restrict__ reg16, const float* __restrict__ reg32,
    float* __restrict__ out) {
  __shared__ u64   lds_runs[256];     // round-A lvl0 intermediate runs
  __shared__ u64   lvlkeys[TOTK];     // final per-level top-64 keys (concat order)
  __shared__ u64   skeys[TOTK];       // NMS-sorted keys
  __shared__ int   slb[TOTK];
  __shared__ float sbx[TOTK * 4];
  __shared__ float sX1[TOTK], sY1[TOTK], sX2[TOTK], sY2[TOTK], sA[TOTK];
  __shared__ u64   rows[TOTK * 3];
  __shared__ u64   svalid[3];
  __shared__ u64   skeep[3];
  __shared__ float lmarr[3];

  const int img  = blockIdx.x;
  const int t    = threadIdx.x;
  const int lane = t & 63, wv = t >> 6;

  const u64* pbase = ws_part + (size_t)img * NCH * TOPK;

  // ---- round A: 4 waves x top64-of-4-runs covers lvl0's 16 runs ----
  {
    const u64* q = pbase + (size_t)(4 * wv) * TOPK;
    u64 a    = q[lane];
    u64 brev = q[64 + 63 - lane];
    u64 c    = q[128 + lane];
    u64 drev = q[192 + 63 - lane];
    lds_runs[wv * 64 + lane] = merge4_top64(a, brev, c, drev, lane);
    if (wv == 3) lvlkeys[128 + lane] = pbase[20 * TOPK + lane];  // lvl2 final
  }
  __syncthreads();

  // ---- round B: wave0 -> lvl0 final (from LDS), wave1 -> lvl1 final ----
  if (wv == 0) {
    u64 a    = lds_runs[lane];
    u64 brev = lds_runs[64 + 63 - lane];
    u64 c    = lds_runs[128 + lane];
    u64 drev = lds_runs[192 + 63 - lane];
    lvlkeys[lane] = merge4_top64(a, brev, c, drev, lane);
  } else if (wv == 1) {
    const u64* q = pbase + (size_t)16 * TOPK;
    u64 a    = q[lane];
    u64 brev = q[64 + 63 - lane];
    u64 c    = q[128 + lane];
    u64 drev = q[192 + 63 - lane];
    lvlkeys[64 + lane] = merge4_top64(a, brev, c, drev, lane);
  }
  __syncthreads();

  // ---- wave0: in-register 192 sort (3 desc runs -> full desc merge).
  //      waves 1-3: decode boxes/labels for the 192 entries (one lvl each).
  if (wv == 0) {
    const u64 HIMASK = 0xFFFFFFFF00000000ull;
    u64 s0 = (lvlkeys[lane] & HIMASK) | (u32)(~(u32)lane);
    int i1 = 64 + 63 - lane;
    u64 s1r = (lvlkeys[i1] & HIMASK) | (u32)(~(u32)i1);
    int i2 = 128 + 63 - lane;
    u64 s2r = (lvlkeys[i2] & HIMASK) | (u32)(~(u32)i2);
    u64 hi_ = bmerge64_desc(u64max(s0, s1r), lane);
    u64 lo_ = bmerge64_desc(u64min(s0, s1r), lane);
    u64 R1   = u64max(lo_, s2r);
    u64 out0 = bmerge64_desc(u64max(hi_, R1), lane);
    u64 out1 = bmerge64_desc(u64min(hi_, R1), lane);
    u64 out2 = bmerge64_desc(u64min(lo_, s2r), lane);
    skeys[lane]       = out0;
    skeys[64 + lane]  = out1;
    skeys[128 + lane] = out2;
  } else {
    int idx = t - 64;                  // 0..191; lvl = wv-1 (uniform per wave)
    const float* reg; int w; int hw; float stride;
    if (wv == 1)      { reg = reg8;  w = 160; hw = 25600; stride = 8.0f;  }
    else if (wv == 2) { reg = reg16; w = 80;  hw = 6400;  stride = 16.0f; }
    else              { reg = reg32; w = 40;  hw = 1600;  stride = 32.0f; }
    reg += (size_t)img * hw * 4;
    u64 key = lvlkeys[idx];
    u32 raw = ~((u32)key);
    int a = (int)(raw / NUM_CLASSES);
    int c = (int)(raw - (u32)a * NUM_CLASSES);
    int ix = a % w, iy = a / w;
    float ax = __fmul_rn((float)ix + 0.5f, stride);
    float ay = __fmul_rn((float)iy + 0.5f, stride);
    float r0 = reg[a*4+0], r1 = reg[a*4+1], r2 = reg[a*4+2], r3 = reg[a*4+3];
    float cx = __fadd_rn(__fmul_rn(r0, stride), ax);
    float cy = __fadd_rn(__fmul_rn(r1, stride), ay);
    float wd = __fmul_rn(expf(r2), stride);
    float ht = __fmul_rn(expf(r3), stride);
    float x1 = __fsub_rn(cx, __fmul_rn(0.5f, wd));
    float y1 = __fsub_rn(cy, __fmul_rn(0.5f, ht));
    float x2 = __fadd_rn(cx, __fmul_rn(0.5f, wd));
    float y2 = __fadd_rn(cy, __fmul_rn(0.5f, ht));
    slb[idx] = c;
    sbx[idx*4+0] = x1; sbx[idx*4+1] = y1;
    sbx[idx*4+2] = x2; sbx[idx*4+3] = y2;
  }
  __syncthreads();

  // ---- NMS setup: per-thread box (sorted order), global |box| max ----
  float sc_r = 0.0f, b0 = 0.0f, b1 = 0.0f, b2 = 0.0f, b3 = 0.0f;
  int p = 0, lb_r = 0;
  if (t < TOTK) {
    u64 key = skeys[t];
    p = (int)(~((u32)key)) & 255;
    sc_r = __uint_as_float((u32)(key >> 32));
    lb_r = slb[p];
    b0 = sbx[p*4+0]; b1 = sbx[p*4+1]; b2 = sbx[p*4+2]; b3 = sbx[p*4+3];
    float lm = fmaxf(fmaxf(fabsf(b0), fabsf(b1)), fmaxf(fabsf(b2), fabsf(b3)));
    #pragma unroll
    for (int d = 32; d > 0; d >>= 1) lm = fmaxf(lm, __shfl_xor(lm, d, 64));
    if (lane == 0) lmarr[wv] = lm;
  }
  __syncthreads();

  const float lmAll = fmaxf(fmaxf(lmarr[0], lmarr[1]), lmarr[2]);
  const float offscale = __fadd_rn(__fmul_rn(2.0f, lmAll), 1.0f);

  float X1 = 0.0f, Y1 = 0.0f, X2 = 0.0f, Y2 = 0.0f, A = 0.0f;
  if (t < TOTK) {
    float off = __fmul_rn((float)lb_r, offscale);
    X1 = __fadd_rn(b0, off); Y1 = __fadd_rn(b1, off);
    X2 = __fadd_rn(b2, off); Y2 = __fadd_rn(b3, off);
    A  = __fmul_rn(__fsub_rn(X2, X1), __fsub_rn(Y2, Y1));
    sX1[t] = X1; sY1[t] = Y1; sX2[t] = X2; sY2[t] = Y2; sA[t] = A;
    u64 bal = __ballot(sc_r > CONF_THRESH);
    if (lane == 0) svalid[wv] = bal;
  }
  __syncthreads();

  if (t < TOTK) {
    u64 r0m = 0, r1m = 0, r2m = 0;
    for (int j = t + 1; j < TOTK; ++j) {
      float xx1 = fmaxf(X1, sX1[j]);
      float yy1 = fmaxf(Y1, sY1[j]);
      float xx2 = fminf(X2, sX2[j]);
      float yy2 = fminf(Y2, sY2[j]);
      float wv2 = fmaxf(1e-10f, __fsub_rn(xx2, xx1));
      float hv = fmaxf(1e-10f, __fsub_rn(yy2, yy1));
      float inter = __fmul_rn(wv2, hv);
      float den = __fsub_rn(__fadd_rn(A, sA[j]), inter);
      float iou = __fdiv_rn(inter, den);
      if (iou > NMS_THRESH) {
        u64 b = 1ull << (j & 63);
        int wd = j >> 6;
        r0m |= (wd == 0) ? b : 0ull;
        r1m |= (wd == 1) ? b : 0ull;
        r2m |= (wd == 2) ? b : 0ull;
      }
    }
    rows[t*3+0] = r0m; rows[t*3+1] = r1m; rows[t*3+2] = r2m;
  }
  __syncthreads();

  if (t < 64) {
    u64 k0 = svalid[0], k1 = svalid[1], k2 = svalid[2];
    #pragma unroll 4
    for (int i = 0; i < 64; ++i) {
      u64 m0 = rows[i*3+0], m1 = rows[i*3+1], m2 = rows[i*3+2];
      u64 sel = 0ull - ((k0 >> i) & 1ull);
      k0 &= ~(m0 & sel); k1 &= ~(m1 & sel); k2 &= ~(m2 & sel);
    }
    #pragma unroll 4
    for (int i = 0; i < 64; ++i) {
      int r = 64 + i;
      u64 m0 = rows[r*3+0], m1 = rows[r*3+1], m2 = rows[r*3+2];
      u64 sel = 0ull - ((k1 >> i) & 1ull);
      k0 &= ~(m0 & sel); k1 &= ~(m1 & sel); k2 &= ~(m2 & sel);
    }
    #pragma unroll 4
    for (int i = 0; i < 64; ++i) {
      int r = 128 + i;
      u64 m0 = rows[r*3+0], m1 = rows[r*3+1], m2 = rows[r*3+2];
      u64 sel = 0ull - ((k2 >> i) & 1ull);
      k0 &= ~(m0 & sel); k1 &= ~(m1 & sel); k2 &= ~(m2 & sel);
    }
    if (t == 0) { skeep[0] = k0; skeep[1] = k1; skeep[2] = k2; }
  }
  __syncthreads();

  if (t < TOTK) {
    float* out_boxes  = out;
    float* out_scores = out + (size_t)BATCH * TOTK * 4;
    float* out_labels = out + (size_t)BATCH * TOTK * 5;
    bool kp = (skeep[t >> 6] >> (t & 63)) & 1ull;
    int gi = img * TOTK + t;
    out_boxes[gi*4+0] = kp ? sbx[p*4+0] : 0.0f;
    out_boxes[gi*4+1] = kp ? sbx[p*4+1] : 0.0f;
    out_boxes[gi*4+2] = kp ? sbx[p*4+2] : 0.0f;
    out_boxes[gi*4+3] = kp ? sbx[p*4+3] : 0.0f;
    out_scores[gi] = kp ? sc_r : 0.0f;
    out_labels[gi] = kp ? (float)lb_r : -1.0f;
  }
}

extern "C" void kernel_launch(void* const* d_in, const int* in_sizes, int n_in,
                              void* d_out, int out_size, void* d_ws, size_t ws_size,
                              hipStream_t stream) {
  const float* obj8  = (const float*)d_in[0];
  const float* cls8  = (const float*)d_in[1];
  const float* reg8  = (const float*)d_in[2];
  const float* obj16 = (const float*)d_in[3];
  const float* cls16 = (const float*)d_in[4];
  const float* reg16 = (const float*)d_in[5];
  const float* obj32 = (const float*)d_in[6];
  const float* cls32 = (const float*)d_in[7];
  const float* reg32 = (const float*)d_in[8];

  // ws layout: part (2688*64 u64 = 1.376 MB)
  u64* ws_part = (u64*)d_ws;

  scan_kernel<<<dim3(BATCH * NCH), dim3(NTHR), 0, stream>>>(
      obj8, cls8, obj16, cls16, obj32, cls32, ws_part);
  merge_nms_kernel<<<dim3(BATCH), dim3(256), 0, stream>>>(
      ws_part, reg8, reg16, reg32, (float*)d_out);
}

// Round 5
// 217.590 us; speedup vs baseline: 1.3536x; 1.1034x over previous
//
#include <hip/hip_runtime.h>

// YOLO post-process, 2 kernels:
//  scan     : per (img, 1600-anchor chunk) exact streaming top-64.
//             R9: latency-focused rewrite of R8 (71us, VALU 30%, HBM 11% --
//             latency-bound, not VALU/HBM-bound):
//               - float4 loads restored (R8's 30 scalar 20B-stride dwords
//                 raised FETCH 50.6->61.3 MB); tail anchor scalar.
//               - ONE gate round (was 5): cheap bound prod=(1+e^-o)(1+e^-c)
//                 ~ 1/score^2 gates into dense LDS worklist; exact OCML
//                 score_key only on ~100-400 survivors. Overflow (wc>WCAP,
//                 adversarial only) -> exact masked-inline fallback.
//               - final top-64 via wave-register tournament (pad to npow<=8
//                 sorted 64-runs, log2 rounds of merge_top64) -- barriers
//                 per block ~43 -> ~8. cs>512 falls back to LDS bitonic.
//             R5 lesson: exec-mask pruning saves nothing; compaction-based
//             worklist is the fix. Margins 50x fast-op err; exact key>thr
//             filter unchanged -> push set bit-identical (absmax 0.0 R2-R8).
//  merge_nms: one block per image; in-register wave merges of sorted runs
//             (R7: top64(A,B)=max(A[l],B[63-l]) + 6-stage shfl merge).

#define NUM_CLASSES 5
#define CONF_THRESH 0.6f
#define NMS_THRESH  0.2f
#define TOPK   64
#define BATCH  128
#define TOTK   192
#define NCH    21      // per image: 16 (lvl0) + 4 (lvl1) + 1 (lvl2), 1600 anchors each
#define CHUNK  1600
#define SCAP   2048    // LDS candidate buffer (u64)
#define NTHR   320     // 5 waves; anchors: 4/thread vectorized + 1 tail
#define WCAP   1600    // worklist capacity (overflow -> exact fallback)

typedef unsigned long long u64;
typedef unsigned int u32;

// Descending bitonic sort of k[0..m) (m pow2), block-cooperative.
// First action is a barrier (covers preceding LDS writes); ends with a barrier.
// (Rare fallback path only, cs > 512.)
__device__ void bitonic_desc(u64* k, int m) {
  for (int kk = 2; kk <= m; kk <<= 1) {
    for (int j = kk >> 1; j > 0; j >>= 1) {
      __syncthreads();
      for (int i = threadIdx.x; i < m; i += blockDim.x) {
        int ixj = i ^ j;
        if (ixj > i) {
          u64 a = k[i], b = k[ixj];
          bool sw = ((i & kk) == 0) ? (a < b) : (a > b);
          if (sw) { k[i] = b; k[ixj] = a; }
        }
      }
    }
  }
  __syncthreads();
}

// In-register bitonic sort of 64 u32 across one wave, descending by lane.
__device__ inline u32 wave_sort64_desc_u32(u32 v, int lane) {
  #pragma unroll
  for (int k = 2; k <= 64; k <<= 1) {
    #pragma unroll
    for (int j = k >> 1; j > 0; j >>= 1) {
      u32 o = __shfl_xor(v, j, 64);
      bool keepMax = (((lane & k) == 0) != ((lane & j) != 0));
      v = keepMax ? (v > o ? v : o) : (v < o ? v : o);
    }
  }
  return v;
}

// In-register bitonic sort of 64 u64 across one wave, descending by lane.
__device__ inline u64 wave_sort64_desc(u64 v, int lane) {
  #pragma unroll
  for (int k = 2; k <= 64; k <<= 1) {
    #pragma unroll
    for (int j = k >> 1; j > 0; j >>= 1) {
      u64 o = __shfl_xor(v, j, 64);
      bool keepMax = (((lane & k) == 0) != ((lane & j) != 0));
      v = keepMax ? (v > o ? v : o) : (v < o ? v : o);
    }
  }
  return v;
}

__device__ __forceinline__ u64 u64max(u64 a, u64 b) { return a > b ? a : b; }
__device__ __forceinline__ u64 u64min(u64 a, u64 b) { return a < b ? a : b; }

// Descending bitonic MERGE of a bitonic 64-seq held one elem/lane.
__device__ __forceinline__ u64 bmerge64_desc(u64 v, int lane) {
  #pragma unroll
  for (int j = 32; j > 0; j >>= 1) {
    u64 o = __shfl_xor(v, j, 64);
    v = ((lane & j) == 0) ? u64max(v, o) : u64min(v, o);
  }
  return v;
}

// a = A[lane] (A desc-sorted), brev = B[63-lane] (B desc-sorted).
// Lane-th element of the desc-sorted top-64 of A∪B.
__device__ __forceinline__ u64 merge_top64(u64 a, u64 brev, int lane) {
  return bmerge64_desc(u64max(a, brev), lane);
}

__device__ __forceinline__ u64 merge4_top64(u64 a, u64 brev, u64 c, u64 drev, int lane) {
  u64 ab = merge_top64(a, brev, lane);
  u64 cd = merge_top64(c, drev, lane);
  u64 cdr = __shfl(cd, 63 - lane, 64);
  return merge_top64(ab, cdr, lane);
}

// score = sqrt(sigmoid(obj)*sigmoid(cls)); key = (score_bits<<32) | ~idx
// reproduces lax.top_k order (value desc, index asc). Bit-exact vs numpy
// (absmax 0.0 R2-R8) -- do not alter the float expressions.
__device__ inline u64 score_key(float so, float cv, int idx) {
  float sc = 1.0f / (1.0f + expf(-cv));
  float s  = sqrtf(__fmul_rn(so, sc));
  return ((u64)__float_as_uint(s) << 32) | (u32)(~(u32)idx);
}

__device__ inline float sigmoidf(float x) { return 1.0f / (1.0f + expf(-x)); }

__global__ __launch_bounds__(NTHR) void scan_kernel(
    const float* __restrict__ obj8,  const float* __restrict__ cls8,
    const float* __restrict__ obj16, const float* __restrict__ cls16,
    const float* __restrict__ obj32, const float* __restrict__ cls32,
    u64* __restrict__ ws_part) {
  __shared__ u64 keys[SCAP];
  __shared__ u32 wl[WCAP];
  __shared__ int cnt;
  __shared__ int wcnt;
  __shared__ u32 sthr[5];

  const int bx  = blockIdx.x;
  const int img = bx / NCH;
  const int c   = bx - img * NCH;
  const int t   = threadIdx.x;
  const int lane = t & 63, wv = t >> 6;

  const float *obj, *cls;
  int hw, off;
  if (c < 16)      { obj = obj8;  cls = cls8;  hw = 25600; off = c * CHUNK; }
  else if (c < 20) { obj = obj16; cls = cls16; hw = 6400;  off = (c - 16) * CHUNK; }
  else             { obj = obj32; cls = cls32; hw = 1600;  off = 0; }
  obj += (size_t)img * hw + off;
  cls += ((size_t)img * hw + off) * NUM_CLASSES;

  // ---- cheap bound pass: ff[k] = (1+e^-obj)(1+e^-cls) ~= 1/score^2
  // (monotone DECREASING in score; fast ops, rel err <= ~2^-21).
  // Anchors: thread t owns 4t..4t+3 (float4 loads) + tail 1280+t (scalar).
  // ff[] only indexed by compile-time constants -> stays in VGPRs (R4).
  float ff[25];
  {
    const float4* c4 = (const float4*)cls + (size_t)t * 5;
    float4 q0 = c4[0], q1 = c4[1], q2 = c4[2], q3 = c4[3], q4 = c4[4];
    float4 ov = ((const float4*)obj)[t];
    float cv[20] = { q0.x,q0.y,q0.z,q0.w, q1.x,q1.y,q1.z,q1.w,
                     q2.x,q2.y,q2.z,q2.w, q3.x,q3.y,q3.z,q3.w,
                     q4.x,q4.y,q4.z,q4.w };
    float dob[4] = { 1.0f + __expf(-ov.x), 1.0f + __expf(-ov.y),
                     1.0f + __expf(-ov.z), 1.0f + __expf(-ov.w) };
    #pragma unroll
    for (int a = 0; a < 4; ++a)
      #pragma unroll
      for (int j = 0; j < 5; ++j)
        ff[a * 5 + j] = dob[a] * (1.0f + __expf(-cv[a * 5 + j]));
    float ot = obj[1280 + t];
    float dot_ = 1.0f + __expf(-ot);
    #pragma unroll
    for (int j = 0; j < 5; ++j) {
      float cvt = cls[(1280 + t) * 5 + j];
      ff[20 + j] = dot_ * (1.0f + __expf(-cvt));
    }
  }

  // seed: per-wave 16th-smallest thread-min-prod (= 16th-largest fast score).
  // >=16 threads/wave have an entry whose TRUE score >= ts -> >=80 exact
  // keys chunk-wide pass the exact filter (>= 64 needed).
  float pmin = ff[0];
  #pragma unroll
  for (int i = 1; i < 25; ++i) pmin = fminf(pmin, ff[i]);
  u32 srt = wave_sort64_desc_u32(__float_as_uint(pmin), lane);
  if (lane == 48) sthr[wv] = srt;        // 16th smallest = 49th largest
  if (t == 0) { cnt = 0; wcnt = 0; }
  __syncthreads();
  u64 thr; float thr_inv;
  {
    float pmax = __uint_as_float(sthr[0]);
    pmax = fmaxf(pmax, __uint_as_float(sthr[1]));
    pmax = fmaxf(pmax, __uint_as_float(sthr[2]));
    pmax = fmaxf(pmax, __uint_as_float(sthr[3]));
    pmax = fmaxf(pmax, __uint_as_float(sthr[4]));
    float ts = sqrtf(__fdiv_rn(1.0f, pmax)) * (1.0f - 1e-4f);
    // key > thr  <=>  score_bits >= bits(ts)  <=>  score >= ts
    thr = ((u64)__float_as_uint(ts) << 32) - 1ull;
    // gate: prod <= thr_inv  <==  score >= ts (2e-4 conservative slack)
    thr_inv = __fdiv_rn(1.0f, __fmul_rn(__fmul_rn(ts, ts), 1.0f - 2e-4f));
  }

  // ---- single gate round: push survivor ids (anchor<<3|class) ----
  #pragma unroll
  for (int a = 0; a < 4; ++a)
    #pragma unroll
    for (int j = 0; j < 5; ++j)
      if (ff[a * 5 + j] <= thr_inv) {
        int p = atomicAdd(&wcnt, 1);
        if (p < WCAP) wl[p] = (u32)(((4 * t + a) << 3) | j);
      }
  #pragma unroll
  for (int j = 0; j < 5; ++j)
    if (ff[20 + j] <= thr_inv) {
      int p = atomicAdd(&wcnt, 1);
      if (p < WCAP) wl[p] = (u32)(((1280 + t) << 3) | j);
    }
  __syncthreads();
  const int wc = wcnt;

  if (wc <= WCAP) {
    // dense exact pass over compacted worklist (~100-400 entries; 1 iter)
    for (int i = t; i < wc; i += NTHR) {
      u32 cd = wl[i];
      int al = (int)(cd >> 3);
      int jj = (int)(cd & 7u);
      float o   = obj[al];
      float cvv = cls[al * 5 + jj];
      u64 key = score_key(sigmoidf(o), cvv, (off + al) * NUM_CLASSES + jj);
      if (key > thr) { int p = atomicAdd(&cnt, 1); if (p < SCAP) keys[p] = key; }
    }
  } else {
    // overflow (adversarial only): exact masked-inline for ALL gated entries
    // (worklist discarded; each gated entry computed exactly once -> exact).
    #pragma unroll
    for (int a = 0; a < 4; ++a)
      #pragma unroll
      for (int j = 0; j < 5; ++j)
        if (ff[a * 5 + j] <= thr_inv) {
          int al = 4 * t + a;
          u64 key = score_key(sigmoidf(obj[al]), cls[al * 5 + j],
                              (off + al) * NUM_CLASSES + j);
          if (key > thr) { int p = atomicAdd(&cnt, 1); if (p < SCAP) keys[p] = key; }
        }
    #pragma unroll
    for (int j = 0; j < 5; ++j)
      if (ff[20 + j] <= thr_inv) {
        int al = 1280 + t;
        u64 key = score_key(sigmoidf(obj[al]), cls[al * 5 + j],
                            (off + al) * NUM_CLASSES + j);
        if (key > thr) { int p = atomicAdd(&cnt, 1); if (p < SCAP) keys[p] = key; }
      }
  }
  __syncthreads();
  int cs = cnt; if (cs > SCAP) cs = SCAP;
  __syncthreads();   // uniform snapshot before pad writes

  // ---- final top-64 (cs >= 80 by seed guarantee) ----
  if (cs > 512) {
    // rare/adversarial fallback: LDS bitonic full sort
    int m = 64; while (m < cs) m <<= 1;
    for (int i = cs + t; i < m; i += NTHR) keys[i] = 0ull;
    bitonic_desc(keys, m);
  } else {
    // wave-register tournament: npow<=8 sorted 64-runs, log2 merge rounds
    int npow = 1; while (npow * 64 < cs) npow <<= 1;   // 2,4,8
    for (int i = cs + t; i < npow * 64; i += NTHR) keys[i] = 0ull;
    __syncthreads();
    for (int r = wv; r < npow; r += 5) {
      u64 v = wave_sort64_desc(keys[r * 64 + lane], lane);
      keys[r * 64 + lane] = v;
    }
    __syncthreads();
    for (int half = npow >> 1; half >= 1; half >>= 1) {
      u64 res = 0ull;
      if (wv < half) {
        u64 a    = keys[(2 * wv) * 64 + lane];
        u64 brev = keys[(2 * wv + 1) * 64 + 63 - lane];
        res = merge_top64(a, brev, lane);
      }
      __syncthreads();                 // all reads complete
      if (wv < half) keys[wv * 64 + lane] = res;
      __syncthreads();
    }
  }
  if (t < TOPK) ws_part[(size_t)bx * TOPK + t] = keys[t];
}

// One block (256 threads = 4 waves) per image: merge levels + decode + NMS.
__global__ __launch_bounds__(256) void merge_nms_kernel(
    const u64* __restrict__ ws_part,
    const float* __restrict__ reg8, const float* __restrict__ reg16, const float* __restrict__ reg32,
    float* __restrict__ out) {
  __shared__ u64   lds_runs[256];     // round-A lvl0 intermediate runs
  __shared__ u64   lvlkeys[TOTK];     // final per-level top-64 keys (concat order)
  __shared__ u64   skeys[TOTK];       // NMS-sorted keys
  __shared__ int   slb[TOTK];
  __shared__ float sbx[TOTK * 4];
  __shared__ float sX1[TOTK], sY1[TOTK], sX2[TOTK], sY2[TOTK], sA[TOTK];
  __shared__ u64   rows[TOTK * 3];
  __shared__ u64   svalid[3];
  __shared__ u64   skeep[3];
  __shared__ float lmarr[3];

  const int img  = blockIdx.x;
  const int t    = threadIdx.x;
  const int lane = t & 63, wv = t >> 6;

  const u64* pbase = ws_part + (size_t)img * NCH * TOPK;

  // ---- round A: 4 waves x top64-of-4-runs covers lvl0's 16 runs ----
  {
    const u64* q = pbase + (size_t)(4 * wv) * TOPK;
    u64 a    = q[lane];
    u64 brev = q[64 + 63 - lane];
    u64 c    = q[128 + lane];
    u64 drev = q[192 + 63 - lane];
    lds_runs[wv * 64 + lane] = merge4_top64(a, brev, c, drev, lane);
    if (wv == 3) lvlkeys[128 + lane] = pbase[20 * TOPK + lane];  // lvl2 final
  }
  __syncthreads();

  // ---- round B: wave0 -> lvl0 final (from LDS), wave1 -> lvl1 final ----
  if (wv == 0) {
    u64 a    = lds_runs[lane];
    u64 brev = lds_runs[64 + 63 - lane];
    u64 c    = lds_runs[128 + lane];
    u64 drev = lds_runs[192 + 63 - lane];
    lvlkeys[lane] = merge4_top64(a, brev, c, drev, lane);
  } else if (wv == 1) {
    const u64* q = pbase + (size_t)16 * TOPK;
    u64 a    = q[lane];
    u64 brev = q[64 + 63 - lane];
    u64 c    = q[128 + lane];
    u64 drev = q[192 + 63 - lane];
    lvlkeys[64 + lane] = merge4_top64(a, brev, c, drev, lane);
  }
  __syncthreads();

  // ---- wave0: in-register 192 sort (3 desc runs -> full desc merge).
  //      waves 1-3: decode boxes/labels for the 192 entries (one lvl each).
  if (wv == 0) {
    const u64 HIMASK = 0xFFFFFFFF00000000ull;
    u64 s0 = (lvlkeys[lane] & HIMASK) | (u32)(~(u32)lane);
    int i1 = 64 + 63 - lane;
    u64 s1r = (lvlkeys[i1] & HIMASK) | (u32)(~(u32)i1);
    int i2 = 128 + 63 - lane;
    u64 s2r = (lvlkeys[i2] & HIMASK) | (u32)(~(u32)i2);
    u64 hi_ = bmerge64_desc(u64max(s0, s1r), lane);
    u64 lo_ = bmerge64_desc(u64min(s0, s1r), lane);
    u64 R1   = u64max(lo_, s2r);
    u64 out0 = bmerge64_desc(u64max(hi_, R1), lane);
    u64 out1 = bmerge64_desc(u64min(hi_, R1), lane);
    u64 out2 = bmerge64_desc(u64min(lo_, s2r), lane);
    skeys[lane]       = out0;
    skeys[64 + lane]  = out1;
    skeys[128 + lane] = out2;
  } else {
    int idx = t - 64;                  // 0..191; lvl = wv-1 (uniform per wave)
    const float* reg; int w; int hw; float stride;
    if (wv == 1)      { reg = reg8;  w = 160; hw = 25600; stride = 8.0f;  }
    else if (wv == 2) { reg = reg16; w = 80;  hw = 6400;  stride = 16.0f; }
    else              { reg = reg32; w = 40;  hw = 1600;  stride = 32.0f; }
    reg += (size_t)img * hw * 4;
    u64 key = lvlkeys[idx];
    u32 raw = ~((u32)key);
    int a = (int)(raw / NUM_CLASSES);
    int c = (int)(raw - (u32)a * NUM_CLASSES);
    int ix = a % w, iy = a / w;
    float ax = __fmul_rn((float)ix + 0.5f, stride);
    float ay = __fmul_rn((float)iy + 0.5f, stride);
    float r0 = reg[a*4+0], r1 = reg[a*4+1], r2 = reg[a*4+2], r3 = reg[a*4+3];
    float cx = __fadd_rn(__fmul_rn(r0, stride), ax);
    float cy = __fadd_rn(__fmul_rn(r1, stride), ay);
    float wd = __fmul_rn(expf(r2), stride);
    float ht = __fmul_rn(expf(r3), stride);
    float x1 = __fsub_rn(cx, __fmul_rn(0.5f, wd));
    float y1 = __fsub_rn(cy, __fmul_rn(0.5f, ht));
    float x2 = __fadd_rn(cx, __fmul_rn(0.5f, wd));
    float y2 = __fadd_rn(cy, __fmul_rn(0.5f, ht));
    slb[idx] = c;
    sbx[idx*4+0] = x1; sbx[idx*4+1] = y1;
    sbx[idx*4+2] = x2; sbx[idx*4+3] = y2;
  }
  __syncthreads();

  // ---- NMS setup: per-thread box (sorted order), global |box| max ----
  float sc_r = 0.0f, b0 = 0.0f, b1 = 0.0f, b2 = 0.0f, b3 = 0.0f;
  int p = 0, lb_r = 0;
  if (t < TOTK) {
    u64 key = skeys[t];
    p = (int)(~((u32)key)) & 255;
    sc_r = __uint_as_float((u32)(key >> 32));
    lb_r = slb[p];
    b0 = sbx[p*4+0]; b1 = sbx[p*4+1]; b2 = sbx[p*4+2]; b3 = sbx[p*4+3];
    float lm = fmaxf(fmaxf(fabsf(b0), fabsf(b1)), fmaxf(fabsf(b2), fabsf(b3)));
    #pragma unroll
    for (int d = 32; d > 0; d >>= 1) lm = fmaxf(lm, __shfl_xor(lm, d, 64));
    if (lane == 0) lmarr[wv] = lm;
  }
  __syncthreads();

  const float lmAll = fmaxf(fmaxf(lmarr[0], lmarr[1]), lmarr[2]);
  const float offscale = __fadd_rn(__fmul_rn(2.0f, lmAll), 1.0f);

  float X1 = 0.0f, Y1 = 0.0f, X2 = 0.0f, Y2 = 0.0f, A = 0.0f;
  if (t < TOTK) {
    float off = __fmul_rn((float)lb_r, offscale);
    X1 = __fadd_rn(b0, off); Y1 = __fadd_rn(b1, off);
    X2 = __fadd_rn(b2, off); Y2 = __fadd_rn(b3, off);
    A  = __fmul_rn(__fsub_rn(X2, X1), __fsub_rn(Y2, Y1));
    sX1[t] = X1; sY1[t] = Y1; sX2[t] = X2; sY2[t] = Y2; sA[t] = A;
    u64 bal = __ballot(sc_r > CONF_THRESH);
    if (lane == 0) svalid[wv] = bal;
  }
  __syncthreads();

  if (t < TOTK) {
    u64 r0m = 0, r1m = 0, r2m = 0;
    for (int j = t + 1; j < TOTK; ++j) {
      float xx1 = fmaxf(X1, sX1[j]);
      float yy1 = fmaxf(Y1, sY1[j]);
      float xx2 = fminf(X2, sX2[j]);
      float yy2 = fminf(Y2, sY2[j]);
      float wv2 = fmaxf(1e-10f, __fsub_rn(xx2, xx1));
      float hv = fmaxf(1e-10f, __fsub_rn(yy2, yy1));
      float inter = __fmul_rn(wv2, hv);
      float den = __fsub_rn(__fadd_rn(A, sA[j]), inter);
      float iou = __fdiv_rn(inter, den);
      if (iou > NMS_THRESH) {
        u64 b = 1ull << (j & 63);
        int wd = j >> 6;
        r0m |= (wd == 0) ? b : 0ull;
        r1m |= (wd == 1) ? b : 0ull;
        r2m |= (wd == 2) ? b : 0ull;
      }
    }
    rows[t*3+0] = r0m; rows[t*3+1] = r1m; rows[t*3+2] = r2m;
  }
  __syncthreads();

  if (t < 64) {
    u64 k0 = svalid[0], k1 = svalid[1], k2 = svalid[2];
    #pragma unroll 4
    for (int i = 0; i < 64; ++i) {
      u64 m0 = rows[i*3+0], m1 = rows[i*3+1], m2 = rows[i*3+2];
      u64 sel = 0ull - ((k0 >> i) & 1ull);
      k0 &= ~(m0 & sel); k1 &= ~(m1 & sel); k2 &= ~(m2 & sel);
    }
    #pragma unroll 4
    for (int i = 0; i < 64; ++i) {
      int r = 64 + i;
      u64 m0 = rows[r*3+0], m1 = rows[r*3+1], m2 = rows[r*3+2];
      u64 sel = 0ull - ((k1 >> i) & 1ull);
      k0 &= ~(m0 & sel); k1 &= ~(m1 & sel); k2 &= ~(m2 & sel);
    }
    #pragma unroll 4
    for (int i = 0; i < 64; ++i) {
      int r = 128 + i;
      u64 m0 = rows[r*3+0], m1 = rows[r*3+1], m2 = rows[r*3+2];
      u64 sel = 0ull - ((k2 >> i) & 1ull);
      k0 &= ~(m0 & sel); k1 &= ~(m1 & sel); k2 &= ~(m2 & sel);
    }
    if (t == 0) { skeep[0] = k0; skeep[1] = k1; skeep[2] = k2; }
  }
  __syncthreads();

  if (t < TOTK) {
    float* out_boxes  = out;
    float* out_scores = out + (size_t)BATCH * TOTK * 4;
    float* out_labels = out + (size_t)BATCH * TOTK * 5;
    bool kp = (skeep[t >> 6] >> (t & 63)) & 1ull;
    int gi = img * TOTK + t;
    out_boxes[gi*4+0] = kp ? sbx[p*4+0] : 0.0f;
    out_boxes[gi*4+1] = kp ? sbx[p*4+1] : 0.0f;
    out_boxes[gi*4+2] = kp ? sbx[p*4+2] : 0.0f;
    out_boxes[gi*4+3] = kp ? sbx[p*4+3] : 0.0f;
    out_scores[gi] = kp ? sc_r : 0.0f;
    out_labels[gi] = kp ? (float)lb_r : -1.0f;
  }
}

extern "C" void kernel_launch(void* const* d_in, const int* in_sizes, int n_in,
                              void* d_out, int out_size, void* d_ws, size_t ws_size,
                              hipStream_t stream) {
  const float* obj8  = (const float*)d_in[0];
  const float* cls8  = (const float*)d_in[1];
  const float* reg8  = (const float*)d_in[2];
  const float* obj16 = (const float*)d_in[3];
  const float* cls16 = (const float*)d_in[4];
  const float* reg16 = (const float*)d_in[5];
  const float* obj32 = (const float*)d_in[6];
  const float* cls32 = (const float*)d_in[7];
  const float* reg32 = (const float*)d_in[8];

  // ws layout: part (2688*64 u64 = 1.376 MB)
  u64* ws_part = (u64*)d_ws;

  scan_kernel<<<dim3(BATCH * NCH), dim3(NTHR), 0, stream>>>(
      obj8, cls8, obj16, cls16, obj32, cls32, ws_part);
  merge_nms_kernel<<<dim3(BATCH), dim3(256), 0, stream>>>(
      ws_part, reg8, reg16, reg32, (float*)d_out);
}